// Round 12
// baseline (117.370 us; speedup 1.0000x reference)
//
#include <hip/hip_runtime.h>

// Block-sparse attention, fp16 QK + bf16 PV MFMA, deferred softmax.
// PAIRED key-block iterations: two independent block-chains interleaved per
// barrier pair (ILP against the exposed latency chain that R8/R11 showed is
// the floor). Single-buffer LDS (37 KB -> 4 WGs/CU), VGPR prefetch of the
// next pair. fp32 in/out. B=2 H=8 S=2048 D=64, BLOCK=64, nb=32.
// Pre-pass: K -> fp16[bh][key][d] (pre-scaled by log2e); V -> bf16 [bh][kb][d][key].

typedef __attribute__((ext_vector_type(8))) short short8;
typedef __attribute__((ext_vector_type(4))) short short4_;
typedef __attribute__((ext_vector_type(4))) float float4_;
typedef __attribute__((ext_vector_type(8))) _Float16 half8_;

#define B_   2
#define H_   8
#define S_   2048
#define D_   64
#define NB_  32
#define KP   72          // padded stride for the (small) P buffer only
#define LOG2E 1.4426950408889634f

__device__ __forceinline__ short f2bf(float f) {            // RNE float->bf16 bits
    union { float f; unsigned int u; } x; x.f = f;
    unsigned int r = x.u + 0x7FFFu + ((x.u >> 16) & 1u);
    return (short)(r >> 16);
}
__device__ __forceinline__ short f2bf_t(float f) {          // truncating float->bf16
    union { float f; unsigned int u; } x; x.f = f;
    return (short)(x.u >> 16);
}
__device__ __forceinline__ float bf2f(short s) {
    union { unsigned int u; float f; } x; x.u = ((unsigned int)(unsigned short)s) << 16;
    return x.f;
}
__device__ __forceinline__ short f2h(float f) {
    _Float16 h = (_Float16)f;
    return __builtin_bit_cast(short, h);
}
// XOR-swizzled offset for a 64x64-short tile stored in granules of 8 shorts.
__device__ __forceinline__ int swz(int row, int gran) {
    return (row << 6) + (((gran ^ row) & 7) << 3);
}

// ---------------- pre-pass: K -> fp16*log2e, V -> per-block-transposed bf16 ----------------
__global__ __launch_bounds__(256)
void preconvert_kernel(const float* __restrict__ K, const float* __restrict__ V,
                       short* __restrict__ Khf, short* __restrict__ Vtb) {
    __shared__ short vn[64 * KP];               // natural bf16 V tile [key][d]
    const int tid = threadIdx.x;
    const int kt  = blockIdx.x;                  // key tile 0..31
    const int bh  = blockIdx.y;                  // 0..15
    const size_t tb = ((size_t)bh * S_ + kt * 64) * D_;

#pragma unroll
    for (int it = 0; it < 4; ++it) {
        int i = tid + it * 256;
        int row = i >> 4, c4 = (i & 15) * 4;
        float4_ kv = *(const float4_*)(K + tb + row * D_ + c4);
        short4_ kh;
#pragma unroll
        for (int e = 0; e < 4; ++e) kh[e] = f2h(kv[e] * LOG2E);   // fold log2e into K
        *(short4_*)(Khf + tb + row * D_ + c4) = kh;
        float4_ vv = *(const float4_*)(V + tb + row * D_ + c4);
        short4_ vb;
#pragma unroll
        for (int e = 0; e < 4; ++e) vb[e] = f2bf(vv[e]);
        *(short4_*)&vn[row * KP + c4] = vb;
    }
    __syncthreads();
    // block-transposed write: Vtb[bh][kt][d][key]  (contiguous 8KB per block)
#pragma unroll
    for (int it = 0; it < 2; ++it) {
        int i = tid + it * 256;
        int rowd = i >> 3, key8 = (i & 7) * 8;
        short8 o;
#pragma unroll
        for (int e = 0; e < 8; ++e) o[e] = vn[(key8 + e) * KP + rowd];
        *(short8*)(Vtb + (((size_t)(bh * NB_ + kt)) * 64 + rowd) * 64 + key8) = o;
    }
}

// ---------------- main: 128-thr WG, 32 q rows, PAIRED blocks per iteration ----------------
__global__ __launch_bounds__(128, 2)
void attn_mfma_pair(const float* __restrict__ Q,
                    const float* __restrict__ Msk,
                    const int* __restrict__ Mat,
                    float* __restrict__ O,
                    const short* __restrict__ Khf_g,
                    const short* __restrict__ Vtb_g) {
    // shorts: Kh slot0 @0, slot1 @4096 | Vt slot0 @8192, slot1 @12288 | P @16384
    __shared__ __align__(16) short lds[4 * 4096 + 2 * 16 * KP];

    const int tid  = threadIdx.x;
    const int wave = tid >> 6;
    const int lane = tid & 63;
    const int c    = lane & 15;
    const int quad = lane >> 4;

    const int qt = blockIdx.x;        // 32-row q tile 0..63
    const int bh = blockIdx.y;        // 0..15
    const int b  = bh / H_;
    const int qb = qt >> 1;           // 64-row block for Mat
    const size_t base = (size_t)bh * S_ * D_;

    // ---- Q A-frags in fp16 (K already carries the log2e scale) ----
    half8_ qa0, qa1;
    {
        const float* qp = Q + base + (size_t)(qt * 32 + wave * 16 + c) * D_ + quad * 8;
#pragma unroll
        for (int e = 0; e < 8; ++e) {
            qa0[e] = (_Float16)qp[e];
            qa1[e] = (_Float16)qp[e + 32];
        }
    }

    float4_ o[4];
    float l_part[4];
#pragma unroll
    for (int t = 0; t < 4; ++t) { o[t][0] = 0.f; o[t][1] = 0.f; o[t][2] = 0.f; o[t][3] = 0.f; }
#pragma unroll
    for (int j = 0; j < 4; ++j) l_part[j] = 0.f;

    // ---- active-block bitmask (uniform across WG) ----
    unsigned long long bmv = __ballot(Mat[qb * NB_ + (lane & 31)] != 0);
    unsigned int mbits = (unsigned int)(bmv & 0xFFFFFFFFull);

    // staging chunk coords: 4 chunks of 8 shorts per 64x64 tile per slot
    int srow[4], sgrn[4], soff[4];
#pragma unroll
    for (int it = 0; it < 4; ++it) {
        int i = tid + it * 128;
        srow[it] = i >> 3;
        sgrn[it] = i & 7;
        soff[it] = swz(srow[it], sgrn[it]);
    }
    // fragment-read swizzled offsets: lo k-step granule quad, hi granule quad+4
    int foff_lo[4], foff_hi[4];
#pragma unroll
    for (int t = 0; t < 4; ++t) {
        foff_lo[t] = swz(t * 16 + c, quad);
        foff_hi[t] = swz(t * 16 + c, quad + 4);
    }

    // prefetch registers for a PAIR of blocks
    short8 sK[8], sV[8];
    float  bias0n[4], bias1n[4];

    // pop a pair from mbits (kb1 duplicates kb0 with kill-bias when odd tail)
    int kb0 = __builtin_ctz(mbits); mbits &= mbits - 1;
    int kb1; bool kill1;
    if (mbits) { kb1 = __builtin_ctz(mbits); mbits &= mbits - 1; kill1 = false; }
    else       { kb1 = kb0; kill1 = true; }

    // ---- prologue: fetch first pair into regs ----
    {
        const short* kh0 = Khf_g + base + (size_t)kb0 * 64 * D_;
        const short* vt0 = Vtb_g + ((size_t)(bh * NB_ + kb0)) * 64 * 64;
        const short* kh1 = Khf_g + base + (size_t)kb1 * 64 * D_;
        const short* vt1 = Vtb_g + ((size_t)(bh * NB_ + kb1)) * 64 * 64;
#pragma unroll
        for (int it = 0; it < 4; ++it) {
            sK[it]     = *(const short8*)(kh0 + srow[it] * 64 + sgrn[it] * 8);
            sV[it]     = *(const short8*)(vt0 + srow[it] * 64 + sgrn[it] * 8);
            sK[4 + it] = *(const short8*)(kh1 + srow[it] * 64 + sgrn[it] * 8);
            sV[4 + it] = *(const short8*)(vt1 + srow[it] * 64 + sgrn[it] * 8);
        }
#pragma unroll
        for (int t = 0; t < 4; ++t) {
            bias0n[t] = -1.0e6f * LOG2E * (1.0f - Msk[(size_t)b * S_ + kb0 * 64 + t * 16 + c]);
            bias1n[t] = kill1 ? -2.0e6f
                              : -1.0e6f * LOG2E * (1.0f - Msk[(size_t)b * S_ + kb1 * 64 + t * 16 + c]);
        }
    }

    for (;;) {
        __syncthreads();   // all waves done reading LDS from previous pair
        // ---- commit current pair to LDS ----
#pragma unroll
        for (int it = 0; it < 4; ++it) {
            *(short8*)&lds[soff[it]]         = sK[it];
            *(short8*)&lds[4096 + soff[it]]  = sK[4 + it];
            *(short8*)&lds[8192 + soff[it]]  = sV[it];
            *(short8*)&lds[12288 + soff[it]] = sV[4 + it];
        }
        float bias0c[4], bias1c[4];
#pragma unroll
        for (int t = 0; t < 4; ++t) { bias0c[t] = bias0n[t]; bias1c[t] = bias1n[t]; }
        __syncthreads();

        // ---- pop + prefetch the NEXT pair (lands during compute) ----
        const bool have_next = (mbits != 0);
        if (have_next) {
            kb0 = __builtin_ctz(mbits); mbits &= mbits - 1;
            if (mbits) { kb1 = __builtin_ctz(mbits); mbits &= mbits - 1; kill1 = false; }
            else       { kb1 = kb0; kill1 = true; }
            const short* kh0 = Khf_g + base + (size_t)kb0 * 64 * D_;
            const short* vt0 = Vtb_g + ((size_t)(bh * NB_ + kb0)) * 64 * 64;
            const short* kh1 = Khf_g + base + (size_t)kb1 * 64 * D_;
            const short* vt1 = Vtb_g + ((size_t)(bh * NB_ + kb1)) * 64 * 64;
#pragma unroll
            for (int it = 0; it < 4; ++it) {
                sK[it]     = *(const short8*)(kh0 + srow[it] * 64 + sgrn[it] * 8);
                sV[it]     = *(const short8*)(vt0 + srow[it] * 64 + sgrn[it] * 8);
                sK[4 + it] = *(const short8*)(kh1 + srow[it] * 64 + sgrn[it] * 8);
                sV[4 + it] = *(const short8*)(vt1 + srow[it] * 64 + sgrn[it] * 8);
            }
#pragma unroll
            for (int t = 0; t < 4; ++t) {
                bias0n[t] = -1.0e6f * LOG2E * (1.0f - Msk[(size_t)b * S_ + kb0 * 64 + t * 16 + c]);
                bias1n[t] = kill1 ? -2.0e6f
                                  : -1.0e6f * LOG2E * (1.0f - Msk[(size_t)b * S_ + kb1 * 64 + t * 16 + c]);
            }
        }

        // ---- scores for BOTH slots, interleaved (independent chains) ----
        float4_ sc0[4], sc1[4];
#pragma unroll
        for (int t = 0; t < 4; ++t) {
            sc0[t][0] = 0.f; sc0[t][1] = 0.f; sc0[t][2] = 0.f; sc0[t][3] = 0.f;
            sc1[t][0] = 0.f; sc1[t][1] = 0.f; sc1[t][2] = 0.f; sc1[t][3] = 0.f;
        }
#pragma unroll
        for (int t = 0; t < 4; ++t) {
            half8_ a0 = __builtin_bit_cast(half8_, *(const short8*)&lds[foff_lo[t]]);
            half8_ a1 = __builtin_bit_cast(half8_, *(const short8*)&lds[foff_hi[t]]);
            half8_ b0 = __builtin_bit_cast(half8_, *(const short8*)&lds[4096 + foff_lo[t]]);
            half8_ b1 = __builtin_bit_cast(half8_, *(const short8*)&lds[4096 + foff_hi[t]]);
            sc0[t] = __builtin_amdgcn_mfma_f32_16x16x32_f16(qa0, a0, sc0[t], 0, 0, 0);
            sc1[t] = __builtin_amdgcn_mfma_f32_16x16x32_f16(qa0, b0, sc1[t], 0, 0, 0);
            sc0[t] = __builtin_amdgcn_mfma_f32_16x16x32_f16(qa1, a1, sc0[t], 0, 0, 0);
            sc1[t] = __builtin_amdgcn_mfma_f32_16x16x32_f16(qa1, b1, sc1[t], 0, 0, 0);
        }

        const int pwoff = 16384 + wave * 16 * KP;

        // ---- slot 0: exp -> P -> PV ----
#pragma unroll
        for (int t = 0; t < 4; ++t) {
#pragma unroll
            for (int j = 0; j < 4; ++j) {
                float p = exp2f(sc0[t][j] + bias0c[t]);
                l_part[j] += p;
                lds[pwoff + (quad * 4 + j) * KP + t * 16 + c] = f2bf_t(p);
            }
        }
        {
            const short* pp = &lds[pwoff + c * KP + quad * 8];
            short8 pa0 = *(const short8*)(pp);
            short8 pa1 = *(const short8*)(pp + 32);
#pragma unroll
            for (int t = 0; t < 4; ++t) {
                short8 vb0 = *(const short8*)&lds[8192 + foff_lo[t]];
                short8 vb1 = *(const short8*)&lds[8192 + foff_hi[t]];
                o[t] = __builtin_amdgcn_mfma_f32_16x16x32_bf16(pa0, vb0, o[t], 0, 0, 0);
                o[t] = __builtin_amdgcn_mfma_f32_16x16x32_bf16(pa1, vb1, o[t], 0, 0, 0);
            }
        }

        // ---- slot 1: exp -> P (same tile; same-wave DS ordering after pa reads) -> PV ----
#pragma unroll
        for (int t = 0; t < 4; ++t) {
#pragma unroll
            for (int j = 0; j < 4; ++j) {
                float p = exp2f(sc1[t][j] + bias1c[t]);
                l_part[j] += p;
                lds[pwoff + (quad * 4 + j) * KP + t * 16 + c] = f2bf_t(p);
            }
        }
        {
            const short* pp = &lds[pwoff + c * KP + quad * 8];
            short8 pa0 = *(const short8*)(pp);
            short8 pa1 = *(const short8*)(pp + 32);
#pragma unroll
            for (int t = 0; t < 4; ++t) {
                short8 vb0 = *(const short8*)&lds[12288 + foff_lo[t]];
                short8 vb1 = *(const short8*)&lds[12288 + foff_hi[t]];
                o[t] = __builtin_amdgcn_mfma_f32_16x16x32_bf16(pa0, vb0, o[t], 0, 0, 0);
                o[t] = __builtin_amdgcn_mfma_f32_16x16x32_bf16(pa1, vb1, o[t], 0, 0, 0);
            }
        }

        if (!have_next) break;
    }

    // ---- epilogue: reduce l across the 16 column-lanes once, normalize, store ----
#pragma unroll
    for (int j = 0; j < 4; ++j) {
        float rs = l_part[j];
        rs += __shfl_xor(rs, 1);
        rs += __shfl_xor(rs, 2);
        rs += __shfl_xor(rs, 4);
        rs += __shfl_xor(rs, 8);
        float inv = 1.0f / rs;
        size_t rowoff = base + (size_t)(qt * 32 + wave * 16 + quad * 4 + j) * D_;
#pragma unroll
        for (int t = 0; t < 4; ++t)
            O[rowoff + t * 16 + c] = o[t][j] * inv;
    }
}

// ---------------- fallback (no workspace): bf16 hi/lo LDS-staging kernel ----------------
__global__ __launch_bounds__(256, 2)
void attn_mfma_fb(const float* __restrict__ Q,
                  const float* __restrict__ K,
                  const float* __restrict__ V,
                  const float* __restrict__ Msk,
                  const int* __restrict__ Mat,
                  float* __restrict__ O) {
    __shared__ __align__(16) short lds[4 * 64 * KP];
    short* Khi = lds;
    short* Klo = lds + 64 * KP;
    short* Vt  = lds + 2 * 64 * KP;
    short* Pl  = lds + 3 * 64 * KP;

    const int tid  = threadIdx.x;
    const int wave = tid >> 6;
    const int lane = tid & 63;
    const int c    = lane & 15;
    const int quad = lane >> 4;

    const int qb = blockIdx.x;
    const int bh = blockIdx.y;
    const int b  = bh / H_;
    const size_t base = (size_t)bh * S_ * D_;

    short8 qh0, qh1, ql0, ql1;
    {
        const float* qp = Q + base + (size_t)(qb * 64 + wave * 16 + c) * D_ + quad * 8;
#pragma unroll
        for (int e = 0; e < 8; ++e) {
            float f0 = qp[e], f1 = qp[e + 32];
            qh0[e] = f2bf(f0); ql0[e] = f2bf(f0 - bf2f(qh0[e]));
            qh1[e] = f2bf(f1); ql1[e] = f2bf(f1 - bf2f(qh1[e]));
        }
    }

    float4_ o[4];
    float l_part[4];
#pragma unroll
    for (int t = 0; t < 4; ++t) { o[t][0] = 0.f; o[t][1] = 0.f; o[t][2] = 0.f; o[t][3] = 0.f; }
#pragma unroll
    for (int j = 0; j < 4; ++j) l_part[j] = 0.f;

    for (int kb = 0; kb < NB_; ++kb) {
        if (Mat[qb * NB_ + kb] == 0) continue;

        __syncthreads();
        {
            const float* kg = K + base + (size_t)kb * 64 * D_;
            const float* vg = V + base + (size_t)kb * 64 * D_;
#pragma unroll
            for (int it = 0; it < 4; ++it) {
                int i = tid + it * 256;
                int row = i >> 4, c4 = (i & 15) * 4;
                float4_ kv = *(const float4_*)(kg + row * D_ + c4);
                short4_ hi, lo;
#pragma unroll
                for (int e = 0; e < 4; ++e) {
                    hi[e] = f2bf(kv[e]);
                    lo[e] = f2bf(kv[e] - bf2f(hi[e]));
                }
                *(short4_*)&Khi[row * KP + c4] = hi;
                *(short4_*)&Klo[row * KP + c4] = lo;
                float4_ vv = *(const float4_*)(vg + row * D_ + c4);
#pragma unroll
                for (int e = 0; e < 4; ++e) Vt[(c4 + e) * KP + row] = f2bf(vv[e]);
            }
        }
        __syncthreads();

        float4_ sc[4];
#pragma unroll
        for (int t = 0; t < 4; ++t) { sc[t][0] = 0.f; sc[t][1] = 0.f; sc[t][2] = 0.f; sc[t][3] = 0.f; }
#pragma unroll
        for (int t = 0; t < 4; ++t) {
            const short* kph = &Khi[(t * 16 + c) * KP + quad * 8];
            const short* kpl = &Klo[(t * 16 + c) * KP + quad * 8];
            short8 kh0 = *(const short8*)(kph);
            short8 kh1 = *(const short8*)(kph + 32);
            short8 kl0 = *(const short8*)(kpl);
            short8 kl1 = *(const short8*)(kpl + 32);
            sc[t] = __builtin_amdgcn_mfma_f32_16x16x32_bf16(qh0, kh0, sc[t], 0, 0, 0);
            sc[t] = __builtin_amdgcn_mfma_f32_16x16x32_bf16(qh1, kh1, sc[t], 0, 0, 0);
            sc[t] = __builtin_amdgcn_mfma_f32_16x16x32_bf16(qh0, kl0, sc[t], 0, 0, 0);
            sc[t] = __builtin_amdgcn_mfma_f32_16x16x32_bf16(qh1, kl1, sc[t], 0, 0, 0);
            sc[t] = __builtin_amdgcn_mfma_f32_16x16x32_bf16(ql0, kh0, sc[t], 0, 0, 0);
            sc[t] = __builtin_amdgcn_mfma_f32_16x16x32_bf16(ql1, kh1, sc[t], 0, 0, 0);
        }

        short* Pw = Pl + wave * 16 * KP;
#pragma unroll
        for (int t = 0; t < 4; ++t) {
            float bias = -1.0e6f * (1.0f - Msk[(size_t)b * S_ + kb * 64 + t * 16 + c]);
#pragma unroll
            for (int j = 0; j < 4; ++j) {
                float p = __expf(sc[t][j] + bias);
                l_part[j] += p;
                Pw[(quad * 4 + j) * KP + t * 16 + c] = f2bf(p);
            }
        }

        const short* pp = Pl + wave * 16 * KP + c * KP + quad * 8;
        short8 pa0 = *(const short8*)(pp);
        short8 pa1 = *(const short8*)(pp + 32);

#pragma unroll
        for (int t = 0; t < 4; ++t) {
            const short* vp = &Vt[(t * 16 + c) * KP + quad * 8];
            short8 vb0 = *(const short8*)(vp);
            short8 vb1 = *(const short8*)(vp + 32);
            o[t] = __builtin_amdgcn_mfma_f32_16x16x32_bf16(pa0, vb0, o[t], 0, 0, 0);
            o[t] = __builtin_amdgcn_mfma_f32_16x16x32_bf16(pa1, vb1, o[t], 0, 0, 0);
        }
    }

#pragma unroll
    for (int j = 0; j < 4; ++j) {
        float rs = l_part[j];
        rs += __shfl_xor(rs, 1);
        rs += __shfl_xor(rs, 2);
        rs += __shfl_xor(rs, 4);
        rs += __shfl_xor(rs, 8);
        float inv = 1.0f / rs;
        size_t rowoff = base + (size_t)(qb * 64 + wave * 16 + quad * 4 + j) * D_;
#pragma unroll
        for (int t = 0; t < 4; ++t)
            O[rowoff + t * 16 + c] = o[t][j] * inv;
    }
}

extern "C" void kernel_launch(void* const* d_in, const int* in_sizes, int n_in,
                              void* d_out, int out_size, void* d_ws, size_t ws_size,
                              hipStream_t stream) {
    const float* q   = (const float*)d_in[0];
    const float* k   = (const float*)d_in[1];
    const float* v   = (const float*)d_in[2];
    const float* msk = (const float*)d_in[3];
    const int*   mat = (const int*)d_in[4];
    float*       out = (float*)d_out;

    const size_t elems = (size_t)B_ * H_ * S_ * D_;      // 2.1M
    const size_t need  = 2 * elems * sizeof(short);      // 8.4 MB
    const int use_pre  = (ws_size >= need) ? 1 : 0;      // deterministic per-call

    short* khf = (short*)d_ws;
    short* vtb = khf + elems;

    if (use_pre) {
        dim3 pgrid(NB_, B_ * H_);
        preconvert_kernel<<<pgrid, dim3(256), 0, stream>>>(k, v, khf, vtb);
        dim3 grid(S_ / 32, B_ * H_);                     // 64 x 16 = 1024 WGs, 128 thr
        attn_mfma_pair<<<grid, dim3(128), 0, stream>>>(q, msk, mat, out, khf, vtb);
    } else {
        dim3 grid(NB_, B_ * H_);
        attn_mfma_fb<<<grid, dim3(256), 0, stream>>>(q, k, v, msk, mat, out);
    }
}

// Round 13
// 110.600 us; speedup vs baseline: 1.0612x; 1.0612x over previous
//
#include <hip/hip_runtime.h>

// Block-sparse attention, fp16 QK + bf16 PV MFMA, deferred softmax, K-SPLIT.
// fp32 in/out. B=2 H=8 S=2048 D=64, BLOCK=64, nb=32.
// R12 lesson: wall = slowest (qb,bh) WG with only 4 WGs/CU and no backfill --
// parallelism-bound, not chain-bound. Deferred-softmax partials are ADDITIVE,
// so split each row-block's active key list across 2 WGs (alternating blocks),
// write unnormalized (o, l) partials to d_ws, combine kernel does
// (o0+o1)/(l0+l1). 256-thr WGs (64 q rows), 24 waves/CU resident.
// Pre-pass: K -> fp16[bh][key][d] (log2e-folded); V -> bf16 [bh][kb][d][key].

typedef __attribute__((ext_vector_type(8))) short short8;
typedef __attribute__((ext_vector_type(4))) short short4_;
typedef __attribute__((ext_vector_type(4))) float float4_;
typedef __attribute__((ext_vector_type(8))) _Float16 half8_;

#define B_   2
#define H_   8
#define S_   2048
#define D_   64
#define NB_  32
#define KP   72          // padded stride for the P tile
#define LOG2E 1.4426950408889634f

__device__ __forceinline__ short f2bf(float f) {            // RNE float->bf16 bits
    union { float f; unsigned int u; } x; x.f = f;
    unsigned int r = x.u + 0x7FFFu + ((x.u >> 16) & 1u);
    return (short)(r >> 16);
}
__device__ __forceinline__ short f2bf_t(float f) {          // truncating float->bf16
    union { float f; unsigned int u; } x; x.f = f;
    return (short)(x.u >> 16);
}
__device__ __forceinline__ float bf2f(short s) {
    union { unsigned int u; float f; } x; x.u = ((unsigned int)(unsigned short)s) << 16;
    return x.f;
}
__device__ __forceinline__ short f2h(float f) {
    _Float16 h = (_Float16)f;
    return __builtin_bit_cast(short, h);
}
// XOR-swizzled offset for a 64x64-short tile stored in granules of 8 shorts.
__device__ __forceinline__ int swz(int row, int gran) {
    return (row << 6) + (((gran ^ row) & 7) << 3);
}

// ---------------- pre-pass: K -> fp16*log2e, V -> per-block-transposed bf16 ----------------
__global__ __launch_bounds__(256)
void preconvert_kernel(const float* __restrict__ K, const float* __restrict__ V,
                       short* __restrict__ Khf, short* __restrict__ Vtb) {
    __shared__ short vn[64 * KP];               // natural bf16 V tile [key][d]
    const int tid = threadIdx.x;
    const int kt  = blockIdx.x;                  // key tile 0..31
    const int bh  = blockIdx.y;                  // 0..15
    const size_t tb = ((size_t)bh * S_ + kt * 64) * D_;

#pragma unroll
    for (int it = 0; it < 4; ++it) {
        int i = tid + it * 256;
        int row = i >> 4, c4 = (i & 15) * 4;
        float4_ kv = *(const float4_*)(K + tb + row * D_ + c4);
        short4_ kh;
#pragma unroll
        for (int e = 0; e < 4; ++e) kh[e] = f2h(kv[e] * LOG2E);   // fold log2e into K
        *(short4_*)(Khf + tb + row * D_ + c4) = kh;
        float4_ vv = *(const float4_*)(V + tb + row * D_ + c4);
        short4_ vb;
#pragma unroll
        for (int e = 0; e < 4; ++e) vb[e] = f2bf(vv[e]);
        *(short4_*)&vn[row * KP + c4] = vb;
    }
    __syncthreads();
    // block-transposed write: Vtb[bh][kt][d][key]  (contiguous 8KB per block)
#pragma unroll
    for (int it = 0; it < 2; ++it) {
        int i = tid + it * 256;
        int rowd = i >> 3, key8 = (i & 7) * 8;
        short8 o;
#pragma unroll
        for (int e = 0; e < 8; ++e) o[e] = vn[(key8 + e) * KP + rowd];
        *(short8*)(Vtb + (((size_t)(bh * NB_ + kt)) * 64 + rowd) * 64 + key8) = o;
    }
}

// ---------------- main: 256-thr WG, 64 q rows, K-split over halves ----------------
__global__ __launch_bounds__(256, 2)
void attn_ks(const float* __restrict__ Q,
             const float* __restrict__ Msk,
             const int* __restrict__ Mat,
             float* __restrict__ Opart,    // [2][B*H*S*D] unnormalized
             float* __restrict__ Lpart,    // [2][B*H*S]
             const short* __restrict__ Khf_g,
             const short* __restrict__ Vtb_g) {
    // shorts: Kh @0 (4096) | Vt @4096 (4096) | P @8192 (4 waves x 16 x KP)
    __shared__ __align__(16) short lds[8192 + 4 * 16 * KP];

    const int tid  = threadIdx.x;
    const int wave = tid >> 6;
    const int lane = tid & 63;
    const int c    = lane & 15;
    const int quad = lane >> 4;

    const int qb   = blockIdx.x;      // 64-row q block 0..31
    const int bh   = blockIdx.y;      // 0..15
    const int half = blockIdx.z;      // 0..1 key-split
    const int b    = bh / H_;
    const size_t base = (size_t)bh * S_ * D_;
    const size_t NOUT = (size_t)B_ * H_ * S_ * D_;

    // ---- Q A-frags in fp16 (K already carries the log2e scale) ----
    half8_ qa0, qa1;
    {
        const float* qp = Q + base + (size_t)(qb * 64 + wave * 16 + c) * D_ + quad * 8;
#pragma unroll
        for (int e = 0; e < 8; ++e) {
            qa0[e] = (_Float16)qp[e];
            qa1[e] = (_Float16)qp[e + 32];
        }
    }

    float4_ o[4];
    float l_part[4];
#pragma unroll
    for (int t = 0; t < 4; ++t) { o[t][0] = 0.f; o[t][1] = 0.f; o[t][2] = 0.f; o[t][3] = 0.f; }
#pragma unroll
    for (int j = 0; j < 4; ++j) l_part[j] = 0.f;

    // ---- active-block bitmask; this WG takes alternating entries ----
    unsigned long long bmv = __ballot(Mat[qb * NB_ + (lane & 31)] != 0);
    unsigned int mb = (unsigned int)(bmv & 0xFFFFFFFFull);
    unsigned int mine = 0;
    {
        unsigned int t = mb; int idx = 0;
        while (t) {
            int k = __builtin_ctz(t); t &= t - 1;
            if ((idx & 1) == half) mine |= (1u << k);
            ++idx;
        }
    }

    // staging chunk coords: 2 chunks of 8 shorts per tile (256 thr x 2 = 512)
    int srow[2], sgrn[2], soff[2];
#pragma unroll
    for (int it = 0; it < 2; ++it) {
        int i = tid + it * 256;
        srow[it] = i >> 3;
        sgrn[it] = i & 7;
        soff[it] = swz(srow[it], sgrn[it]);
    }
    // fragment-read swizzled offsets: lo k-step granule quad, hi granule quad+4
    int foff_lo[4], foff_hi[4];
#pragma unroll
    for (int t = 0; t < 4; ++t) {
        foff_lo[t] = swz(t * 16 + c, quad);
        foff_hi[t] = swz(t * 16 + c, quad + 4);
    }

    if (mine) {
        short8 sK[2], sV[2];
        float  biasn[4];
        int kb = __builtin_ctz(mine); mine &= mine - 1;
        {
            const short* kh = Khf_g + base + (size_t)kb * 64 * D_;
            const short* vt = Vtb_g + ((size_t)(bh * NB_ + kb)) * 64 * 64;
#pragma unroll
            for (int it = 0; it < 2; ++it) {
                sK[it] = *(const short8*)(kh + srow[it] * 64 + sgrn[it] * 8);
                sV[it] = *(const short8*)(vt + srow[it] * 64 + sgrn[it] * 8);
            }
#pragma unroll
            for (int t = 0; t < 4; ++t)
                biasn[t] = -1.0e6f * LOG2E * (1.0f - Msk[(size_t)b * S_ + kb * 64 + t * 16 + c]);
        }

        for (;;) {
            __syncthreads();   // all waves done reading LDS from previous block
#pragma unroll
            for (int it = 0; it < 2; ++it) {
                *(short8*)&lds[soff[it]]        = sK[it];
                *(short8*)&lds[4096 + soff[it]] = sV[it];
            }
            float biasc[4];
#pragma unroll
            for (int t = 0; t < 4; ++t) biasc[t] = biasn[t];
            __syncthreads();

            const bool have_next = (mine != 0);
            if (have_next) {
                kb = __builtin_ctz(mine); mine &= mine - 1;
                const short* kh = Khf_g + base + (size_t)kb * 64 * D_;
                const short* vt = Vtb_g + ((size_t)(bh * NB_ + kb)) * 64 * 64;
#pragma unroll
                for (int it = 0; it < 2; ++it) {
                    sK[it] = *(const short8*)(kh + srow[it] * 64 + sgrn[it] * 8);
                    sV[it] = *(const short8*)(vt + srow[it] * 64 + sgrn[it] * 8);
                }
#pragma unroll
                for (int t = 0; t < 4; ++t)
                    biasn[t] = -1.0e6f * LOG2E * (1.0f - Msk[(size_t)b * S_ + kb * 64 + t * 16 + c]);
            }

            // ---- scores (log2e-scaled): 8 fp16 MFMA ----
            float4_ sc[4];
#pragma unroll
            for (int t = 0; t < 4; ++t) { sc[t][0] = 0.f; sc[t][1] = 0.f; sc[t][2] = 0.f; sc[t][3] = 0.f; }
#pragma unroll
            for (int t = 0; t < 4; ++t) {
                half8_ kb0 = __builtin_bit_cast(half8_, *(const short8*)&lds[foff_lo[t]]);
                half8_ kb1 = __builtin_bit_cast(half8_, *(const short8*)&lds[foff_hi[t]]);
                sc[t] = __builtin_amdgcn_mfma_f32_16x16x32_f16(qa0, kb0, sc[t], 0, 0, 0);
                sc[t] = __builtin_amdgcn_mfma_f32_16x16x32_f16(qa1, kb1, sc[t], 0, 0, 0);
            }

            // ---- P = exp2(s + bias'); per-lane l partial; P -> per-wave LDS ----
            const int pwoff = 8192 + wave * 16 * KP;
#pragma unroll
            for (int t = 0; t < 4; ++t) {
#pragma unroll
                for (int j = 0; j < 4; ++j) {
                    float p = exp2f(sc[t][j] + biasc[t]);
                    l_part[j] += p;
                    lds[pwoff + (quad * 4 + j) * KP + t * 16 + c] = f2bf_t(p);
                }
            }

            // ---- P A-frags (same-wave DS ordering) ----
            const short* pp = &lds[pwoff + c * KP + quad * 8];
            short8 pa0 = *(const short8*)(pp);
            short8 pa1 = *(const short8*)(pp + 32);

            // ---- O += P * V (bf16) ----
#pragma unroll
            for (int t = 0; t < 4; ++t) {
                short8 vb0 = *(const short8*)&lds[4096 + foff_lo[t]];
                short8 vb1 = *(const short8*)&lds[4096 + foff_hi[t]];
                o[t] = __builtin_amdgcn_mfma_f32_16x16x32_bf16(pa0, vb0, o[t], 0, 0, 0);
                o[t] = __builtin_amdgcn_mfma_f32_16x16x32_bf16(pa1, vb1, o[t], 0, 0, 0);
            }

            if (!have_next) break;
        }
    }

    // ---- epilogue: reduce l across 16 column-lanes, write UNNORMALIZED partials ----
#pragma unroll
    for (int j = 0; j < 4; ++j) {
        float rs = l_part[j];
        rs += __shfl_xor(rs, 1);
        rs += __shfl_xor(rs, 2);
        rs += __shfl_xor(rs, 4);
        rs += __shfl_xor(rs, 8);
        const int srow_ = qb * 64 + wave * 16 + quad * 4 + j;
        float* Op = Opart + (size_t)half * NOUT + base + (size_t)srow_ * D_;
#pragma unroll
        for (int t = 0; t < 4; ++t)
            Op[t * 16 + c] = o[t][j];
        if (c == 0)
            Lpart[(size_t)half * (B_ * H_ * S_) + (size_t)bh * S_ + srow_] = rs;
    }
}

// ---------------- combine: out = (o0+o1)/(l0+l1) ----------------
__global__ __launch_bounds__(256)
void combine_kernel(const float* __restrict__ Opart,
                    const float* __restrict__ Lpart,
                    float* __restrict__ O) {
    const size_t N = (size_t)B_ * H_ * S_ * D_;
    size_t i = ((size_t)blockIdx.x * 256 + threadIdx.x) * 4;
    if (i >= N) return;
    int row = (int)(i >> 6);                       // bh*S + s  (D=64)
    float4_ a = *(const float4_*)(Opart + i);
    float4_ bq = *(const float4_*)(Opart + N + i);
    float l = Lpart[row] + Lpart[(size_t)B_ * H_ * S_ + row];
    float inv = 1.0f / l;
    float4_ r;
    r[0] = (a[0] + bq[0]) * inv; r[1] = (a[1] + bq[1]) * inv;
    r[2] = (a[2] + bq[2]) * inv; r[3] = (a[3] + bq[3]) * inv;
    *(float4_*)(O + i) = r;
}

// ---------------- fallback (no workspace): bf16 hi/lo LDS-staging kernel ----------------
__global__ __launch_bounds__(256, 2)
void attn_mfma_fb(const float* __restrict__ Q,
                  const float* __restrict__ K,
                  const float* __restrict__ V,
                  const float* __restrict__ Msk,
                  const int* __restrict__ Mat,
                  float* __restrict__ O) {
    __shared__ __align__(16) short lds[4 * 64 * KP];
    short* Khi = lds;
    short* Klo = lds + 64 * KP;
    short* Vt  = lds + 2 * 64 * KP;
    short* Pl  = lds + 3 * 64 * KP;

    const int tid  = threadIdx.x;
    const int wave = tid >> 6;
    const int lane = tid & 63;
    const int c    = lane & 15;
    const int quad = lane >> 4;

    const int qb = blockIdx.x;
    const int bh = blockIdx.y;
    const int b  = bh / H_;
    const size_t base = (size_t)bh * S_ * D_;

    short8 qh0, qh1, ql0, ql1;
    {
        const float* qp = Q + base + (size_t)(qb * 64 + wave * 16 + c) * D_ + quad * 8;
#pragma unroll
        for (int e = 0; e < 8; ++e) {
            float f0 = qp[e], f1 = qp[e + 32];
            qh0[e] = f2bf(f0); ql0[e] = f2bf(f0 - bf2f(qh0[e]));
            qh1[e] = f2bf(f1); ql1[e] = f2bf(f1 - bf2f(qh1[e]));
        }
    }

    float4_ o[4];
    float l_part[4];
#pragma unroll
    for (int t = 0; t < 4; ++t) { o[t][0] = 0.f; o[t][1] = 0.f; o[t][2] = 0.f; o[t][3] = 0.f; }
#pragma unroll
    for (int j = 0; j < 4; ++j) l_part[j] = 0.f;

    for (int kb = 0; kb < NB_; ++kb) {
        if (Mat[qb * NB_ + kb] == 0) continue;

        __syncthreads();
        {
            const float* kg = K + base + (size_t)kb * 64 * D_;
            const float* vg = V + base + (size_t)kb * 64 * D_;
#pragma unroll
            for (int it = 0; it < 4; ++it) {
                int i = tid + it * 256;
                int row = i >> 4, c4 = (i & 15) * 4;
                float4_ kv = *(const float4_*)(kg + row * D_ + c4);
                short4_ hi, lo;
#pragma unroll
                for (int e = 0; e < 4; ++e) {
                    hi[e] = f2bf(kv[e]);
                    lo[e] = f2bf(kv[e] - bf2f(hi[e]));
                }
                *(short4_*)&Khi[row * KP + c4] = hi;
                *(short4_*)&Klo[row * KP + c4] = lo;
                float4_ vv = *(const float4_*)(vg + row * D_ + c4);
#pragma unroll
                for (int e = 0; e < 4; ++e) Vt[(c4 + e) * KP + row] = f2bf(vv[e]);
            }
        }
        __syncthreads();

        float4_ sc[4];
#pragma unroll
        for (int t = 0; t < 4; ++t) { sc[t][0] = 0.f; sc[t][1] = 0.f; sc[t][2] = 0.f; sc[t][3] = 0.f; }
#pragma unroll
        for (int t = 0; t < 4; ++t) {
            const short* kph = &Khi[(t * 16 + c) * KP + quad * 8];
            const short* kpl = &Klo[(t * 16 + c) * KP + quad * 8];
            short8 kh0 = *(const short8*)(kph);
            short8 kh1 = *(const short8*)(kph + 32);
            short8 kl0 = *(const short8*)(kpl);
            short8 kl1 = *(const short8*)(kpl + 32);
            sc[t] = __builtin_amdgcn_mfma_f32_16x16x32_bf16(qh0, kh0, sc[t], 0, 0, 0);
            sc[t] = __builtin_amdgcn_mfma_f32_16x16x32_bf16(qh1, kh1, sc[t], 0, 0, 0);
            sc[t] = __builtin_amdgcn_mfma_f32_16x16x32_bf16(qh0, kl0, sc[t], 0, 0, 0);
            sc[t] = __builtin_amdgcn_mfma_f32_16x16x32_bf16(qh1, kl1, sc[t], 0, 0, 0);
            sc[t] = __builtin_amdgcn_mfma_f32_16x16x32_bf16(ql0, kh0, sc[t], 0, 0, 0);
            sc[t] = __builtin_amdgcn_mfma_f32_16x16x32_bf16(ql1, kh1, sc[t], 0, 0, 0);
        }

        short* Pw = Pl + wave * 16 * KP;
#pragma unroll
        for (int t = 0; t < 4; ++t) {
            float bias = -1.0e6f * (1.0f - Msk[(size_t)b * S_ + kb * 64 + t * 16 + c]);
#pragma unroll
            for (int j = 0; j < 4; ++j) {
                float p = __expf(sc[t][j] + bias);
                l_part[j] += p;
                Pw[(quad * 4 + j) * KP + t * 16 + c] = f2bf(p);
            }
        }

        const short* pp = Pl + wave * 16 * KP + c * KP + quad * 8;
        short8 pa0 = *(const short8*)(pp);
        short8 pa1 = *(const short8*)(pp + 32);

#pragma unroll
        for (int t = 0; t < 4; ++t) {
            const short* vp = &Vt[(t * 16 + c) * KP + quad * 8];
            short8 vb0 = *(const short8*)(vp);
            short8 vb1 = *(const short8*)(vp + 32);
            o[t] = __builtin_amdgcn_mfma_f32_16x16x32_bf16(pa0, vb0, o[t], 0, 0, 0);
            o[t] = __builtin_amdgcn_mfma_f32_16x16x32_bf16(pa1, vb1, o[t], 0, 0, 0);
        }
    }

#pragma unroll
    for (int j = 0; j < 4; ++j) {
        float rs = l_part[j];
        rs += __shfl_xor(rs, 1);
        rs += __shfl_xor(rs, 2);
        rs += __shfl_xor(rs, 4);
        rs += __shfl_xor(rs, 8);
        float inv = 1.0f / rs;
        size_t rowoff = base + (size_t)(qb * 64 + wave * 16 + quad * 4 + j) * D_;
#pragma unroll
        for (int t = 0; t < 4; ++t)
            O[rowoff + t * 16 + c] = o[t][j] * inv;
    }
}

extern "C" void kernel_launch(void* const* d_in, const int* in_sizes, int n_in,
                              void* d_out, int out_size, void* d_ws, size_t ws_size,
                              hipStream_t stream) {
    const float* q   = (const float*)d_in[0];
    const float* k   = (const float*)d_in[1];
    const float* v   = (const float*)d_in[2];
    const float* msk = (const float*)d_in[3];
    const int*   mat = (const int*)d_in[4];
    float*       out = (float*)d_out;

    const size_t elems = (size_t)B_ * H_ * S_ * D_;          // 2,097,152
    const size_t need  = 2 * elems * sizeof(short)           // khf + vtb
                       + 2 * elems * sizeof(float)           // Opart
                       + 2 * (size_t)B_ * H_ * S_ * sizeof(float);  // Lpart
    const int use_pre  = (ws_size >= need) ? 1 : 0;          // deterministic per-call

    short* khf   = (short*)d_ws;
    short* vtb   = khf + elems;
    float* opart = (float*)(vtb + elems);
    float* lpart = opart + 2 * elems;

    if (use_pre) {
        dim3 pgrid(NB_, B_ * H_);
        preconvert_kernel<<<pgrid, dim3(256), 0, stream>>>(k, v, khf, vtb);
        dim3 grid(NB_, B_ * H_, 2);                          // 32 x 16 x 2 = 1024 WGs, 256 thr
        attn_ks<<<grid, dim3(256), 0, stream>>>(q, msk, mat, opart, lpart, khf, vtb);
        combine_kernel<<<dim3((unsigned)(elems / 4 / 256)), dim3(256), 0, stream>>>(opart, lpart, out);
    } else {
        dim3 grid(NB_, B_ * H_);
        attn_mfma_fb<<<grid, dim3(256), 0, stream>>>(q, k, v, msk, mat, out);
    }
}

// Round 14
// 107.839 us; speedup vs baseline: 1.0884x; 1.0256x over previous
//
#include <hip/hip_runtime.h>

// Block-sparse attention, fp16 QK + bf16 PV MFMA, deferred softmax,
// FUSED 2-way key split: one 512-thr WG (8 waves) per (qb, bh).
// Waves 0-3 = key half 0, waves 4-7 = key half 1 (same 64 q rows); both halves
// run identical iteration counts (kill-bias padding) so WG barriers are legal;
// final (o0+o1)/(l0+l1) merge via LDS -- no combine kernel, no global partials.
// fp32 in/out. B=2 H=8 S=2048 D=64, BLOCK=64, nb=32.
// Pre-pass: K -> fp16[bh][key][d] (log2e-folded); V -> bf16 [bh][kb][d][key].

typedef __attribute__((ext_vector_type(8))) short short8;
typedef __attribute__((ext_vector_type(4))) short short4_;
typedef __attribute__((ext_vector_type(4))) float float4_;
typedef __attribute__((ext_vector_type(8))) _Float16 half8_;

#define B_   2
#define H_   8
#define S_   2048
#define D_   64
#define NB_  32
#define KP   72          // padded stride for the P tiles
#define LOG2E 1.4426950408889634f

__device__ __forceinline__ short f2bf(float f) {            // RNE float->bf16 bits
    union { float f; unsigned int u; } x; x.f = f;
    unsigned int r = x.u + 0x7FFFu + ((x.u >> 16) & 1u);
    return (short)(r >> 16);
}
__device__ __forceinline__ short f2bf_t(float f) {          // truncating float->bf16
    union { float f; unsigned int u; } x; x.f = f;
    return (short)(x.u >> 16);
}
__device__ __forceinline__ float bf2f(short s) {
    union { unsigned int u; float f; } x; x.u = ((unsigned int)(unsigned short)s) << 16;
    return x.f;
}
__device__ __forceinline__ short f2h(float f) {
    _Float16 h = (_Float16)f;
    return __builtin_bit_cast(short, h);
}
// XOR-swizzled offset for a 64x64-short tile stored in granules of 8 shorts.
__device__ __forceinline__ int swz(int row, int gran) {
    return (row << 6) + (((gran ^ row) & 7) << 3);
}

// ---------------- pre-pass: K -> fp16*log2e, V -> per-block-transposed bf16 ----------------
__global__ __launch_bounds__(256)
void preconvert_kernel(const float* __restrict__ K, const float* __restrict__ V,
                       short* __restrict__ Khf, short* __restrict__ Vtb) {
    __shared__ short vn[64 * KP];               // natural bf16 V tile [key][d]
    const int tid = threadIdx.x;
    const int kt  = blockIdx.x;                  // key tile 0..31
    const int bh  = blockIdx.y;                  // 0..15
    const size_t tb = ((size_t)bh * S_ + kt * 64) * D_;

#pragma unroll
    for (int it = 0; it < 4; ++it) {
        int i = tid + it * 256;
        int row = i >> 4, c4 = (i & 15) * 4;
        float4_ kv = *(const float4_*)(K + tb + row * D_ + c4);
        short4_ kh;
#pragma unroll
        for (int e = 0; e < 4; ++e) kh[e] = f2h(kv[e] * LOG2E);   // fold log2e into K
        *(short4_*)(Khf + tb + row * D_ + c4) = kh;
        float4_ vv = *(const float4_*)(V + tb + row * D_ + c4);
        short4_ vb;
#pragma unroll
        for (int e = 0; e < 4; ++e) vb[e] = f2bf(vv[e]);
        *(short4_*)&vn[row * KP + c4] = vb;
    }
    __syncthreads();
    // block-transposed write: Vtb[bh][kt][d][key]  (contiguous 8KB per block)
#pragma unroll
    for (int it = 0; it < 2; ++it) {
        int i = tid + it * 256;
        int rowd = i >> 3, key8 = (i & 7) * 8;
        short8 o;
#pragma unroll
        for (int e = 0; e < 8; ++e) o[e] = vn[(key8 + e) * KP + rowd];
        *(short8*)(Vtb + (((size_t)(bh * NB_ + kt)) * 64 + rowd) * 64 + key8) = o;
    }
}

// ---------------- main: 512-thr WG, fused 2-way key split + in-LDS merge ----------------
__global__ __launch_bounds__(512, 4)
void attn_fused(const float* __restrict__ Q,
                const float* __restrict__ Msk,
                const int* __restrict__ Mat,
                float* __restrict__ O,
                const short* __restrict__ Khf_g,
                const short* __restrict__ Vtb_g) {
    // shorts: Kh h0 @0, h1 @4096 | Vt h0 @8192, h1 @12288 | P @16384 (8 waves x 16*KP)
    // epilogue overlays the K/V area (first 32 KB) as float for the o/l merge.
    __shared__ __align__(16) short lds[16384 + 8 * 16 * KP];

    const int tid  = threadIdx.x;
    const int wave = tid >> 6;        // 0..7
    const int half = wave >> 2;       // key half 0/1
    const int qtw  = wave & 3;        // 16-row q tile within the 64-row block
    const int lane = tid & 63;
    const int c    = lane & 15;
    const int quad = lane >> 4;
    const int hid  = tid & 255;       // thread id within the half (for staging)

    const int qb = blockIdx.x;        // 64-row q block 0..31
    const int bh = blockIdx.y;        // 0..15
    const int b  = bh / H_;
    const size_t base = (size_t)bh * S_ * D_;

    const int hbK = half * 4096;          // this half's K tile base
    const int hbV = 8192 + half * 4096;   // this half's V tile base

    // ---- Q A-frags in fp16 (K carries the log2e scale) ----
    half8_ qa0, qa1;
    {
        const float* qp = Q + base + (size_t)(qb * 64 + qtw * 16 + c) * D_ + quad * 8;
#pragma unroll
        for (int e = 0; e < 8; ++e) {
            qa0[e] = (_Float16)qp[e];
            qa1[e] = (_Float16)qp[e + 32];
        }
    }

    float4_ o[4];
    float l_part[4];
#pragma unroll
    for (int t = 0; t < 4; ++t) { o[t][0] = 0.f; o[t][1] = 0.f; o[t][2] = 0.f; o[t][3] = 0.f; }
#pragma unroll
    for (int j = 0; j < 4; ++j) l_part[j] = 0.f;

    // ---- active-block bitmask; this half takes alternating entries ----
    unsigned long long bmv = __ballot(Mat[qb * NB_ + (lane & 31)] != 0);
    unsigned int mb = (unsigned int)(bmv & 0xFFFFFFFFull);
    const int nact  = __popc(mb);
    const int niter = (nact + 1) >> 1;    // identical for both halves (kill-padded)
    unsigned int mine = 0;
    {
        unsigned int tb2 = mb; int idx = 0;
        while (tb2) {
            int k = __builtin_ctz(tb2); tb2 &= tb2 - 1;
            if ((idx & 1) == half) mine |= (1u << k);
            ++idx;
        }
    }

    // staging chunk coords: 2 chunks of 8 shorts per tile (256 thr/half x 2 = 512)
    int srow[2], sgrn[2], soff[2];
#pragma unroll
    for (int it = 0; it < 2; ++it) {
        int i = hid + it * 256;
        srow[it] = i >> 3;
        sgrn[it] = i & 7;
        soff[it] = swz(srow[it], sgrn[it]);
    }
    int foff_lo[4], foff_hi[4];
#pragma unroll
    for (int t = 0; t < 4; ++t) {
        foff_lo[t] = swz(t * 16 + c, quad);
        foff_hi[t] = swz(t * 16 + c, quad + 4);
    }

    // ---- prologue: prefetch this half's first block (or kill pad) ----
    short8 sK[2], sV[2];
    float  biasn[4];
    int kb; bool kill;
    if (mine) { kb = __builtin_ctz(mine); mine &= mine - 1; kill = false; }
    else      { kb = __builtin_ctz(mb); kill = true; }
    {
        const short* kh = Khf_g + base + (size_t)kb * 64 * D_;
        const short* vt = Vtb_g + ((size_t)(bh * NB_ + kb)) * 64 * 64;
#pragma unroll
        for (int it = 0; it < 2; ++it) {
            sK[it] = *(const short8*)(kh + srow[it] * 64 + sgrn[it] * 8);
            sV[it] = *(const short8*)(vt + srow[it] * 64 + sgrn[it] * 8);
        }
#pragma unroll
        for (int t = 0; t < 4; ++t)
            biasn[t] = kill ? -2.0e6f
                            : -1.0e6f * LOG2E * (1.0f - Msk[(size_t)b * S_ + kb * 64 + t * 16 + c]);
    }

    for (int it2 = 0; it2 < niter; ++it2) {
        __syncthreads();   // all waves done reading LDS from previous iteration
#pragma unroll
        for (int s = 0; s < 2; ++s) {
            *(short8*)&lds[hbK + soff[s]] = sK[s];
            *(short8*)&lds[hbV + soff[s]] = sV[s];
        }
        float biasc[4];
#pragma unroll
        for (int t = 0; t < 4; ++t) biasc[t] = biasn[t];
        __syncthreads();

        // ---- prefetch this half's next block (lands during compute) ----
        if (it2 + 1 < niter) {
            if (mine) { kb = __builtin_ctz(mine); mine &= mine - 1; kill = false; }
            else      { kill = true; }   // keep kb; stale sK/sV are harmless (bias kills)
            if (!kill) {
                const short* kh = Khf_g + base + (size_t)kb * 64 * D_;
                const short* vt = Vtb_g + ((size_t)(bh * NB_ + kb)) * 64 * 64;
#pragma unroll
                for (int s = 0; s < 2; ++s) {
                    sK[s] = *(const short8*)(kh + srow[s] * 64 + sgrn[s] * 8);
                    sV[s] = *(const short8*)(vt + srow[s] * 64 + sgrn[s] * 8);
                }
#pragma unroll
                for (int t = 0; t < 4; ++t)
                    biasn[t] = -1.0e6f * LOG2E * (1.0f - Msk[(size_t)b * S_ + kb * 64 + t * 16 + c]);
            } else {
#pragma unroll
                for (int t = 0; t < 4; ++t) biasn[t] = -2.0e6f;
            }
        }

        // ---- scores (log2e-scaled): 8 fp16 MFMA from this half's K tile ----
        float4_ sc[4];
#pragma unroll
        for (int t = 0; t < 4; ++t) { sc[t][0] = 0.f; sc[t][1] = 0.f; sc[t][2] = 0.f; sc[t][3] = 0.f; }
#pragma unroll
        for (int t = 0; t < 4; ++t) {
            half8_ kb0 = __builtin_bit_cast(half8_, *(const short8*)&lds[hbK + foff_lo[t]]);
            half8_ kb1 = __builtin_bit_cast(half8_, *(const short8*)&lds[hbK + foff_hi[t]]);
            sc[t] = __builtin_amdgcn_mfma_f32_16x16x32_f16(qa0, kb0, sc[t], 0, 0, 0);
            sc[t] = __builtin_amdgcn_mfma_f32_16x16x32_f16(qa1, kb1, sc[t], 0, 0, 0);
        }

        // ---- P = exp2(s + bias'); per-lane l partial; P -> per-wave LDS tile ----
        const int pwoff = 16384 + wave * 16 * KP;
#pragma unroll
        for (int t = 0; t < 4; ++t) {
#pragma unroll
            for (int j = 0; j < 4; ++j) {
                float p = exp2f(sc[t][j] + biasc[t]);
                l_part[j] += p;
                lds[pwoff + (quad * 4 + j) * KP + t * 16 + c] = f2bf_t(p);
            }
        }

        // ---- P A-frags (same-wave DS ordering) ----
        const short* pp = &lds[pwoff + c * KP + quad * 8];
        short8 pa0 = *(const short8*)(pp);
        short8 pa1 = *(const short8*)(pp + 32);

        // ---- O += P * V (bf16) from this half's V tile ----
#pragma unroll
        for (int t = 0; t < 4; ++t) {
            short8 vb0 = *(const short8*)&lds[hbV + foff_lo[t]];
            short8 vb1 = *(const short8*)&lds[hbV + foff_hi[t]];
            o[t] = __builtin_amdgcn_mfma_f32_16x16x32_bf16(pa0, vb0, o[t], 0, 0, 0);
            o[t] = __builtin_amdgcn_mfma_f32_16x16x32_bf16(pa1, vb1, o[t], 0, 0, 0);
        }
    }

    // ---- in-LDS merge: half1 publishes (o, l); half0 adds, normalizes, stores ----
    __syncthreads();
    float* fl = (float*)lds;                  // overlays the K/V area (first 32 KB)
    if (half == 1) {
        const int idx = ((wave - 4) * 64 + lane) * 21;   // 21-stride: conflict-free
#pragma unroll
        for (int t = 0; t < 4; ++t)
#pragma unroll
            for (int j = 0; j < 4; ++j) fl[idx + t * 4 + j] = o[t][j];
#pragma unroll
        for (int j = 0; j < 4; ++j) fl[idx + 16 + j] = l_part[j];
    }
    __syncthreads();
    if (half == 0) {
        const int idx = (wave * 64 + lane) * 21;
#pragma unroll
        for (int j = 0; j < 4; ++j) {
            float rs = l_part[j] + fl[idx + 16 + j];
            rs += __shfl_xor(rs, 1);
            rs += __shfl_xor(rs, 2);
            rs += __shfl_xor(rs, 4);
            rs += __shfl_xor(rs, 8);
            float inv = 1.0f / rs;
            size_t rowoff = base + (size_t)(qb * 64 + qtw * 16 + quad * 4 + j) * D_;
#pragma unroll
            for (int t = 0; t < 4; ++t)
                O[rowoff + t * 16 + c] = (o[t][j] + fl[idx + t * 4 + j]) * inv;
        }
    }
}

// ---------------- fallback (no workspace): bf16 hi/lo LDS-staging kernel ----------------
__global__ __launch_bounds__(256, 2)
void attn_mfma_fb(const float* __restrict__ Q,
                  const float* __restrict__ K,
                  const float* __restrict__ V,
                  const float* __restrict__ Msk,
                  const int* __restrict__ Mat,
                  float* __restrict__ O) {
    __shared__ __align__(16) short lds[4 * 64 * KP];
    short* Khi = lds;
    short* Klo = lds + 64 * KP;
    short* Vt  = lds + 2 * 64 * KP;
    short* Pl  = lds + 3 * 64 * KP;

    const int tid  = threadIdx.x;
    const int wave = tid >> 6;
    const int lane = tid & 63;
    const int c    = lane & 15;
    const int quad = lane >> 4;

    const int qb = blockIdx.x;
    const int bh = blockIdx.y;
    const int b  = bh / H_;
    const size_t base = (size_t)bh * S_ * D_;

    short8 qh0, qh1, ql0, ql1;
    {
        const float* qp = Q + base + (size_t)(qb * 64 + wave * 16 + c) * D_ + quad * 8;
#pragma unroll
        for (int e = 0; e < 8; ++e) {
            float f0 = qp[e], f1 = qp[e + 32];
            qh0[e] = f2bf(f0); ql0[e] = f2bf(f0 - bf2f(qh0[e]));
            qh1[e] = f2bf(f1); ql1[e] = f2bf(f1 - bf2f(qh1[e]));
        }
    }

    float4_ o[4];
    float l_part[4];
#pragma unroll
    for (int t = 0; t < 4; ++t) { o[t][0] = 0.f; o[t][1] = 0.f; o[t][2] = 0.f; o[t][3] = 0.f; }
#pragma unroll
    for (int j = 0; j < 4; ++j) l_part[j] = 0.f;

    for (int kb = 0; kb < NB_; ++kb) {
        if (Mat[qb * NB_ + kb] == 0) continue;

        __syncthreads();
        {
            const float* kg = K + base + (size_t)kb * 64 * D_;
            const float* vg = V + base + (size_t)kb * 64 * D_;
#pragma unroll
            for (int it = 0; it < 4; ++it) {
                int i = tid + it * 256;
                int row = i >> 4, c4 = (i & 15) * 4;
                float4_ kv = *(const float4_*)(kg + row * D_ + c4);
                short4_ hi, lo;
#pragma unroll
                for (int e = 0; e < 4; ++e) {
                    hi[e] = f2bf(kv[e]);
                    lo[e] = f2bf(kv[e] - bf2f(hi[e]));
                }
                *(short4_*)&Khi[row * KP + c4] = hi;
                *(short4_*)&Klo[row * KP + c4] = lo;
                float4_ vv = *(const float4_*)(vg + row * D_ + c4);
#pragma unroll
                for (int e = 0; e < 4; ++e) Vt[(c4 + e) * KP + row] = f2bf(vv[e]);
            }
        }
        __syncthreads();

        float4_ sc[4];
#pragma unroll
        for (int t = 0; t < 4; ++t) { sc[t][0] = 0.f; sc[t][1] = 0.f; sc[t][2] = 0.f; sc[t][3] = 0.f; }
#pragma unroll
        for (int t = 0; t < 4; ++t) {
            const short* kph = &Khi[(t * 16 + c) * KP + quad * 8];
            const short* kpl = &Klo[(t * 16 + c) * KP + quad * 8];
            short8 kh0 = *(const short8*)(kph);
            short8 kh1 = *(const short8*)(kph + 32);
            short8 kl0 = *(const short8*)(kpl);
            short8 kl1 = *(const short8*)(kpl + 32);
            sc[t] = __builtin_amdgcn_mfma_f32_16x16x32_bf16(qh0, kh0, sc[t], 0, 0, 0);
            sc[t] = __builtin_amdgcn_mfma_f32_16x16x32_bf16(qh1, kh1, sc[t], 0, 0, 0);
            sc[t] = __builtin_amdgcn_mfma_f32_16x16x32_bf16(qh0, kl0, sc[t], 0, 0, 0);
            sc[t] = __builtin_amdgcn_mfma_f32_16x16x32_bf16(qh1, kl1, sc[t], 0, 0, 0);
            sc[t] = __builtin_amdgcn_mfma_f32_16x16x32_bf16(ql0, kh0, sc[t], 0, 0, 0);
            sc[t] = __builtin_amdgcn_mfma_f32_16x16x32_bf16(ql1, kh1, sc[t], 0, 0, 0);
        }

        short* Pw = Pl + wave * 16 * KP;
#pragma unroll
        for (int t = 0; t < 4; ++t) {
            float bias = -1.0e6f * (1.0f - Msk[(size_t)b * S_ + kb * 64 + t * 16 + c]);
#pragma unroll
            for (int j = 0; j < 4; ++j) {
                float p = __expf(sc[t][j] + bias);
                l_part[j] += p;
                Pw[(quad * 4 + j) * KP + t * 16 + c] = f2bf(p);
            }
        }

        const short* pp = Pl + wave * 16 * KP + c * KP + quad * 8;
        short8 pa0 = *(const short8*)(pp);
        short8 pa1 = *(const short8*)(pp + 32);

#pragma unroll
        for (int t = 0; t < 4; ++t) {
            const short* vp = &Vt[(t * 16 + c) * KP + quad * 8];
            short8 vb0 = *(const short8*)(vp);
            short8 vb1 = *(const short8*)(vp + 32);
            o[t] = __builtin_amdgcn_mfma_f32_16x16x32_bf16(pa0, vb0, o[t], 0, 0, 0);
            o[t] = __builtin_amdgcn_mfma_f32_16x16x32_bf16(pa1, vb1, o[t], 0, 0, 0);
        }
    }

#pragma unroll
    for (int j = 0; j < 4; ++j) {
        float rs = l_part[j];
        rs += __shfl_xor(rs, 1);
        rs += __shfl_xor(rs, 2);
        rs += __shfl_xor(rs, 4);
        rs += __shfl_xor(rs, 8);
        float inv = 1.0f / rs;
        size_t rowoff = base + (size_t)(qb * 64 + wave * 16 + quad * 4 + j) * D_;
#pragma unroll
        for (int t = 0; t < 4; ++t)
            O[rowoff + t * 16 + c] = o[t][j] * inv;
    }
}

extern "C" void kernel_launch(void* const* d_in, const int* in_sizes, int n_in,
                              void* d_out, int out_size, void* d_ws, size_t ws_size,
                              hipStream_t stream) {
    const float* q   = (const float*)d_in[0];
    const float* k   = (const float*)d_in[1];
    const float* v   = (const float*)d_in[2];
    const float* msk = (const float*)d_in[3];
    const int*   mat = (const int*)d_in[4];
    float*       out = (float*)d_out;

    const size_t elems = (size_t)B_ * H_ * S_ * D_;      // 2,097,152
    const size_t need  = 2 * elems * sizeof(short);      // khf + vtb = 8.4 MB
    const int use_pre  = (ws_size >= need) ? 1 : 0;      // deterministic per-call

    short* khf = (short*)d_ws;
    short* vtb = khf + elems;

    if (use_pre) {
        dim3 pgrid(NB_, B_ * H_);
        preconvert_kernel<<<pgrid, dim3(256), 0, stream>>>(k, v, khf, vtb);
        dim3 grid(NB_, B_ * H_);                         // 32 x 16 = 512 WGs, 512 thr
        attn_fused<<<grid, dim3(512), 0, stream>>>(q, msk, mat, out, khf, vtb);
    } else {
        dim3 grid(NB_, B_ * H_);
        attn_mfma_fb<<<grid, dim3(256), 0, stream>>>(q, k, v, msk, mat, out);
    }
}